// Round 14
// baseline (428.152 us; speedup 1.0000x reference)
//
#include <hip/hip_runtime.h>

#define NN 50000
#define EE 800000
#define LMD 768
#define HD 192
#define SLOPE 0.01f

typedef short bf16x8 __attribute__((ext_vector_type(8)));
typedef float f32x4 __attribute__((ext_vector_type(4)));
typedef unsigned short u16;

__device__ __forceinline__ float lrelu(float v){ return v > 0.f ? v : SLOPE * v; }

__device__ __forceinline__ u16 f2bf(float f){
    unsigned u = __float_as_uint(f);
    u += 0x7FFF + ((u >> 16) & 1u);
    return (u16)(u >> 16);
}
__device__ __forceinline__ float bf2f(u16 v){
    return __uint_as_float(((unsigned)v) << 16);
}
__device__ __forceinline__ bf16x8 as_bf8(float4 v){
    union { float4 f; bf16x8 b; } u; u.f = v; return u.b;
}

// ================= L0: weight prep (pure) =================
__global__ __launch_bounds__(256) void k_prep(
    const float* __restrict__ W0, const float* __restrict__ W1,
    const float* __restrict__ W2, const float* __restrict__ W3,
    const float* __restrict__ Win, const float* __restrict__ Wc1,
    const float* __restrict__ Wc2, const float* __restrict__ Wo1,
    u16* __restrict__ out)
{
    int m = blockIdx.y;
    int idx = blockIdx.x * 256 + threadIdx.x;
    const float* src; int nelem; int K;
    switch (m) {
      case 0: src = W0;  nelem = 32*768;  K = 768; break;
      case 1: src = W1;  nelem = 32*768;  K = 768; break;
      case 2: src = W2;  nelem = 32*768;  K = 768; break;
      case 3: src = W3;  nelem = 32*768;  K = 768; break;
      case 4: src = Win; nelem = 192*192; K = 192; break;
      case 5: src = Wc1; nelem = 192*192; K = 192; break;
      case 6: src = Wc2; nelem = 192*192; K = 192; break;
      default: src = Wo1; nelem = 96*192; K = 192; break;
    }
    if (idx >= nelem) return;
    u16 v = f2bf(src[idx]);
    int c = idx / K, k = idx - c * K;
    int cb = c >> 4, lr = c & 15;
    int sg = k >> 5, kk = k & 31, hi = kk >> 3, j = kk & 7;
    int lane = hi * 16 + lr;
    size_t dst;
    if (m < 4)      dst = (size_t)m * 24576 + (sg * 2 + cb) * 512 + lane * 8 + j;
    else if (m < 7) dst = 98304 + (size_t)(m - 4) * 36864 + (sg * 12 + cb) * 512 + lane * 8 + j;
    else            dst = 208896 + (size_t)(sg * 6 + cb) * 512 + lane * 8 + j;
    out[dst] = v;
}

// ================= L1: big branches STRIDED (x<192) + degree count riders (x>=192) =================
__global__ __launch_bounds__(256, 3) void k_branch(
    const float* __restrict__ des, const float* __restrict__ twt,
    const float* __restrict__ prex, const float* __restrict__ xx,
    const u16* __restrict__ Wf,
    const float* __restrict__ bd, const float* __restrict__ btx,
    const float* __restrict__ btw, const float* __restrict__ btr,
    u16* __restrict__ h,
    const int* __restrict__ ei, int* __restrict__ deg)
{
    __shared__ u16 Abuf[16][776];
    __shared__ float scr[4][16][32];

    if (blockIdx.x >= 192) {
        int rid = blockIdx.y * 64 + (blockIdx.x - 192);
        for (int e = rid * 256 + threadIdx.x; e < EE; e += 65536)
            atomicAdd(&deg[ei[EE + e]], 1);
        return;
    }

    const int br = blockIdx.y;
    const float* A; const float* bias; int colBase;
    switch (br) {
      case 0:  A = des;  bias = bd;  colBase = 64;  break;
      case 1:  A = twt;  bias = btx; colBase = 96;  break;
      case 2:  A = prex; bias = btw; colBase = 128; break;
      default: A = xx;   bias = btr; colBase = 160; break;
    }

    const int t0 = threadIdx.x, w = t0 >> 6, l = t0 & 63;
    const int hi = l >> 4, lr = l & 15;

    bf16x8 Bfr[12];
    {
        const u16* wp = Wf + br * 24576;
        #pragma unroll
        for (int cc = 0; cc < 6; ++cc)
            #pragma unroll
            for (int cb = 0; cb < 2; ++cb)
                Bfr[cc * 2 + cb] = *(const bf16x8*)(wp + ((w * 6 + cc) * 2 + cb) * 512 + l * 8);
    }

    const int rrow = t0 >> 4;
    const int col0 = (t0 & 15) * 2;
    const float bias0 = bias[col0], bias1 = bias[col0 + 1];

    float4 f4[12];
    int tile = blockIdx.x;
    {
        const float* ab = A + (size_t)tile * 12288 + w * 3072 + l * 4;
        #pragma unroll
        for (int i = 0; i < 12; ++i) f4[i] = *(const float4*)(ab + i * 256);
    }

    for (; tile < 3125; tile += 192) {
        asm volatile("s_waitcnt vmcnt(0)" ::: "memory");
        #pragma unroll
        for (int i = 0; i < 12; ++i) {
            const int rr = i / 3, third = i % 3;
            uint2 pk;
            pk.x = (unsigned)f2bf(f4[i].x) | ((unsigned)f2bf(f4[i].y) << 16);
            pk.y = (unsigned)f2bf(f4[i].z) | ((unsigned)f2bf(f4[i].w) << 16);
            *(uint2*)&Abuf[w * 4 + rr][third * 256 + l * 4] = pk;
        }
        const int tnext = tile + 192;
        if (tnext < 3125) {
            const float* ab = A + (size_t)tnext * 12288 + w * 3072 + l * 4;
            #pragma unroll
            for (int i = 0; i < 12; ++i) f4[i] = *(const float4*)(ab + i * 256);
        }
        __syncthreads();

        f32x4 acc[2] = {};
        #pragma unroll
        for (int cc = 0; cc < 6; ++cc) {
            const int cg = w * 6 + cc;
            bf16x8 af = *(const bf16x8*)&Abuf[lr][cg * 32 + hi * 8];
            acc[0] = __builtin_amdgcn_mfma_f32_16x16x32_bf16(af, Bfr[cc * 2 + 0], acc[0], 0, 0, 0);
            acc[1] = __builtin_amdgcn_mfma_f32_16x16x32_bf16(af, Bfr[cc * 2 + 1], acc[1], 0, 0, 0);
        }
        #pragma unroll
        for (int cb = 0; cb < 2; ++cb)
            #pragma unroll
            for (int rg = 0; rg < 4; ++rg)
                scr[w][hi * 4 + rg][cb * 16 + lr] = acc[cb][rg];
        __syncthreads();

        float2 s; s.x = 0.f; s.y = 0.f;
        #pragma unroll
        for (int ww = 0; ww < 4; ++ww) {
            float2 p = *(const float2*)&scr[ww][rrow][col0];
            s.x += p.x; s.y += p.y;
        }
        unsigned pk = (unsigned)f2bf(lrelu(s.x + bias0)) | ((unsigned)f2bf(lrelu(s.y + bias1)) << 16);
        *(unsigned*)&h[((size_t)tile * 16 + rrow) * HD + colBase + col0] = pk;
    }
}

// ================= L2: small branches (x<1563) + scan1 riders (x>=1563) =================
__global__ __launch_bounds__(256) void k_small_scan(
    const float* __restrict__ nprop, const float* __restrict__ ncat,
    const float* __restrict__ Wp, const float* __restrict__ bp,
    const float* __restrict__ Wc, const float* __restrict__ bc,
    u16* __restrict__ h,
    const int* __restrict__ deg, int* __restrict__ rp, int* __restrict__ part,
    float* __restrict__ dinv, float* __restrict__ invdeg)
{
    if (blockIdx.x >= 1563) {
        __shared__ int sh[256];
        int sb = blockIdx.x - 1563;
        int tid = threadIdx.x;
        int i = sb * 256 + tid;
        int x = (i < NN) ? deg[i] : 0;
        if (i < NN) {
            float d = (float)(x + 1);
            dinv[i] = rsqrtf(d);
            invdeg[i] = 1.0f / d;
        }
        sh[tid] = x;
        __syncthreads();
        for (int off = 1; off < 256; off <<= 1) {
            int y = (tid >= off) ? sh[tid - off] : 0;
            __syncthreads();
            sh[tid] += y;
            __syncthreads();
        }
        if (i < NN) rp[i] = sh[tid] - x;
        if (tid == 255) part[sb] = sh[255];
        return;
    }

    __shared__ float sWp[160], sbp[32], sWc[32], sbc[32];
    int t = threadIdx.x;
    if (t < 160) sWp[t] = Wp[t];
    else if (t < 192) sbp[t - 160] = bp[t - 160];
    else if (t < 224) sWc[t - 192] = Wc[t - 192];
    else              sbc[t - 224] = bc[t - 224];
    __syncthreads();

    int idx = blockIdx.x * 256 + t;
    if (idx >= NN * 8) return;
    int row = idx >> 3, g = idx & 7;
    float o[8];
    if (g < 4) {
        float np[5];
        #pragma unroll
        for (int k = 0; k < 5; ++k) np[k] = nprop[row * 5 + k];
        #pragma unroll
        for (int j = 0; j < 8; ++j) {
            int c = g * 8 + j;
            float a = sbp[c];
            #pragma unroll
            for (int k = 0; k < 5; ++k) a += np[k] * sWp[c * 5 + k];
            o[j] = lrelu(a);
        }
    } else {
        float nc = ncat[row];
        #pragma unroll
        for (int j = 0; j < 8; ++j) {
            int cc = (g - 4) * 8 + j;
            o[j] = lrelu(sbc[cc] + nc * sWc[cc]);
        }
    }
    uint4 pk;
    pk.x = (unsigned)f2bf(o[0]) | ((unsigned)f2bf(o[1]) << 16);
    pk.y = (unsigned)f2bf(o[2]) | ((unsigned)f2bf(o[3]) << 16);
    pk.z = (unsigned)f2bf(o[4]) | ((unsigned)f2bf(o[5]) << 16);
    pk.w = (unsigned)f2bf(o[6]) | ((unsigned)f2bf(o[7]) << 16);
    *(uint4*)&h[(size_t)row * HD + g * 8] = pk;
}

// ================= hidden GEMM + optional graph-build rider role =================
// ROLE: 1 = scan3 (x>=391), 2 = fill (x>=391)
template<bool BIAS, bool LRELU, int ROLE>
__global__ __launch_bounds__(512) void k_hgemm(
    const u16* __restrict__ A, const u16* __restrict__ Wf,
    const float* __restrict__ bias, u16* __restrict__ out,
    const int* __restrict__ deg, int* __restrict__ rp, const int* __restrict__ part,
    int* __restrict__ cursor, const int* __restrict__ ei,
    int* __restrict__ cs, float* __restrict__ nrm, const float* __restrict__ dinv)
{
    __shared__ u16 Bs[36864];
    if (ROLE == 1 && blockIdx.x >= 391) {
        int sb = blockIdx.x - 391;
        int tid = threadIdx.x;
        if (tid < 256) {
            int pre = 0;
            for (int j = 0; j < sb; ++j) pre += part[j];
            int i = sb * 256 + tid;
            if (i < NN) {
                int v = rp[i] + pre;
                rp[i] = v;
                cursor[i] = v;
                if (i == NN - 1) rp[NN] = v + deg[i];
            }
        }
        return;
    }
    if (ROLE == 2 && blockIdx.x >= 391) {
        int rid = blockIdx.x - 391;
        for (int e = rid * 512 + threadIdx.x; e < EE; e += 102400) {
            int s = ei[e], d = ei[EE + e];
            int pos = atomicAdd(&cursor[d], 1);
            cs[pos] = s;
            nrm[pos] = dinv[s] * dinv[d];
        }
        return;
    }

    const int t = threadIdx.x, w = t >> 6, l = t & 63;
    const int hi = l >> 4, lr = l & 15;
    const int rowBase = blockIdx.x * 128;
    {
        const uint4* s_ = (const uint4*)Wf; uint4* d_ = (uint4*)Bs;
        #pragma unroll
        for (int i = 0; i < 9; ++i) d_[i * 512 + t] = s_[i * 512 + t];
    }
    int r0 = rowBase + w * 16 + lr;
    int rowc = r0 < NN ? r0 : NN - 1;
    const u16* ap = A + (size_t)rowc * HD;
    float4 araw[6];
    #pragma unroll
    for (int sg = 0; sg < 6; ++sg) {
        araw[sg] = *(const float4*)(ap + sg * 32 + hi * 8);
        asm volatile("" :: "v"(araw[sg].x), "v"(araw[sg].y), "v"(araw[sg].z), "v"(araw[sg].w));
    }
    __syncthreads();

    f32x4 acc[12] = {};
    #pragma unroll
    for (int sg = 0; sg < 6; ++sg) {
        bf16x8 af = as_bf8(araw[sg]);
        #pragma unroll
        for (int cb = 0; cb < 12; ++cb) {
            bf16x8 bf = *(const bf16x8*)(Bs + (sg * 12 + cb) * 512 + l * 8);
            acc[cb] = __builtin_amdgcn_mfma_f32_16x16x32_bf16(af, bf, acc[cb], 0, 0, 0);
        }
    }

    #pragma unroll
    for (int cb = 0; cb < 12; ++cb) {
        int cl = cb * 16 + lr;
        float bv = BIAS ? bias[cl] : 0.f;
        #pragma unroll
        for (int rg = 0; rg < 4; ++rg) {
            int r = rowBase + w * 16 + hi * 4 + rg;
            if (r < NN) {
                float v = acc[cb][rg] + bv;
                if (LRELU) v = lrelu(v);
                out[(size_t)r * HD + cl] = f2bf(v);
            }
        }
    }
}

// ================= agg core: 48 lanes gather one node's 192 cols (4/lane) =================
__device__ __forceinline__ void agg_node(const u16* __restrict__ hW,
    const int* __restrict__ rp, const int* __restrict__ cs, const float* __restrict__ nrm,
    const float* __restrict__ invdeg, const float* __restrict__ bias,
    int v, int f0, float& a0, float& a1, float& a2, float& a3)
{
    int s0 = rp[v], s1 = rp[v + 1];
    float4 bv = *reinterpret_cast<const float4*>(bias + f0);
    ushort4 hv = *reinterpret_cast<const ushort4*>(hW + (size_t)v * HD + f0);
    float idg = invdeg[v];
    a0 = bf2f(hv.x) * idg + bv.x;
    a1 = bf2f(hv.y) * idg + bv.y;
    a2 = bf2f(hv.z) * idg + bv.z;
    a3 = bf2f(hv.w) * idg + bv.w;
    int i = s0;
    for (; i + 8 <= s1; i += 8) {
        int c[8]; float n[8]; ushort4 g[8];
        #pragma unroll
        for (int j = 0; j < 8; ++j) { c[j] = cs[i + j]; n[j] = nrm[i + j]; }
        #pragma unroll
        for (int j = 0; j < 8; ++j)
            g[j] = *reinterpret_cast<const ushort4*>(hW + (size_t)c[j] * HD + f0);
        #pragma unroll
        for (int j = 0; j < 8; ++j) {
            a0 += bf2f(g[j].x) * n[j]; a1 += bf2f(g[j].y) * n[j];
            a2 += bf2f(g[j].z) * n[j]; a3 += bf2f(g[j].w) * n[j];
        }
    }
    for (; i < s1; ++i) {
        int c = cs[i]; float n = nrm[i];
        ushort4 g = *reinterpret_cast<const ushort4*>(hW + (size_t)c * HD + f0);
        a0 += bf2f(g.x) * n; a1 += bf2f(g.y) * n; a2 += bf2f(g.z) * n; a3 += bf2f(g.w) * n;
    }
}

// ================= L5': agg(+b_c1) fused with @W_c2^T -> out (16 nodes/block) =================
__global__ __launch_bounds__(256) void k_aggemm(const u16* __restrict__ hW,
    const int* __restrict__ rp, const int* __restrict__ cs, const float* __restrict__ nrm,
    const float* __restrict__ invdeg, const float* __restrict__ bias,
    const u16* __restrict__ Wf, u16* __restrict__ out)
{
    __shared__ u16 tile[16 * 192];      // swizzled bf16 agg rows (6 KB)
    const int lane = threadIdx.x, wv = threadIdx.y;
    const int rowBase = blockIdx.x * 16;

    // preload B frags (3 col-blocks per wave), independent of agg
    bf16x8 Bfr[18];
    #pragma unroll
    for (int sg = 0; sg < 6; ++sg)
        #pragma unroll
        for (int c3 = 0; c3 < 3; ++c3)
            Bfr[sg * 3 + c3] = *(const bf16x8*)(Wf + (sg * 12 + wv * 3 + c3) * 512 + lane * 8);

    if (lane < 48) {
        const int f0 = lane * 4;
        const int chunk = f0 >> 3, within = f0 & 7;
        for (int it = 0; it < 4; ++it) {
            int rr = wv * 4 + it;
            float a0, a1, a2, a3;
            agg_node(hW, rp, cs, nrm, invdeg, bias, rowBase + rr, f0, a0, a1, a2, a3);
            ushort4 o;
            o.x = f2bf(a0); o.y = f2bf(a1); o.z = f2bf(a2); o.w = f2bf(a3);
            *(ushort4*)&tile[rr * 192 + (chunk ^ (rr & 7)) * 8 + within] = o;
        }
    }
    __syncthreads();

    const int hi = lane >> 4, lr = lane & 15;
    f32x4 acc[3] = {};
    #pragma unroll
    for (int sg = 0; sg < 6; ++sg) {
        int ck = (sg * 4 + hi) ^ (lr & 7);
        bf16x8 af = *(const bf16x8*)&tile[lr * 192 + ck * 8];
        #pragma unroll
        for (int c3 = 0; c3 < 3; ++c3)
            acc[c3] = __builtin_amdgcn_mfma_f32_16x16x32_bf16(af, Bfr[sg * 3 + c3], acc[c3], 0, 0, 0);
    }
    #pragma unroll
    for (int c3 = 0; c3 < 3; ++c3) {
        int cl = (wv * 3 + c3) * 16 + lr;
        #pragma unroll
        for (int rg = 0; rg < 4; ++rg) {
            int r = rowBase + hi * 4 + rg;
            out[(size_t)r * HD + cl] = f2bf(acc[c3][rg]);
        }
    }
}

// ================= L7': agg(+b_c2) fused with em=lrelu(@Wo1+b1) and out=em@Wo2+b2 =================
__global__ __launch_bounds__(256) void k_aggfinal(const u16* __restrict__ hW,
    const int* __restrict__ rp, const int* __restrict__ cs, const float* __restrict__ nrm,
    const float* __restrict__ invdeg, const float* __restrict__ bias,
    const u16* __restrict__ Wf, const float* __restrict__ b1,
    const float* __restrict__ W2, const float* __restrict__ b2,
    float* __restrict__ em, float* __restrict__ outp)
{
    __shared__ u16 tile[16 * 192];
    __shared__ float scrF[3][16][2];
    const int lane = threadIdx.x, wv = threadIdx.y;
    const int rowBase = blockIdx.x * 16;

    bf16x8 Bfr[12];
    if (wv < 3) {
        #pragma unroll
        for (int sg = 0; sg < 6; ++sg)
            #pragma unroll
            for (int ci = 0; ci < 2; ++ci)
                Bfr[sg * 2 + ci] = *(const bf16x8*)(Wf + (sg * 6 + wv * 2 + ci) * 512 + lane * 8);
    }

    if (lane < 48) {
        const int f0 = lane * 4;
        const int chunk = f0 >> 3, within = f0 & 7;
        for (int it = 0; it < 4; ++it) {
            int rr = wv * 4 + it;
            float a0, a1, a2, a3;
            agg_node(hW, rp, cs, nrm, invdeg, bias, rowBase + rr, f0, a0, a1, a2, a3);
            ushort4 o;
            o.x = f2bf(a0); o.y = f2bf(a1); o.z = f2bf(a2); o.w = f2bf(a3);
            *(ushort4*)&tile[rr * 192 + (chunk ^ (rr & 7)) * 8 + within] = o;
        }
    }
    __syncthreads();

    const int hi = lane >> 4, lr = lane & 15;
    if (wv < 3) {
        float w2v[2][2], bv1[2];
        #pragma unroll
        for (int ci = 0; ci < 2; ++ci) {
            int cl = (wv * 2 + ci) * 16 + lr;
            bv1[ci] = b1[cl];
            w2v[0][ci] = W2[cl];
            w2v[1][ci] = W2[96 + cl];
        }
        f32x4 acc[2] = {};
        #pragma unroll
        for (int sg = 0; sg < 6; ++sg) {
            int ck = (sg * 4 + hi) ^ (lr & 7);
            bf16x8 af = *(const bf16x8*)&tile[lr * 192 + ck * 8];
            #pragma unroll
            for (int ci = 0; ci < 2; ++ci)
                acc[ci] = __builtin_amdgcn_mfma_f32_16x16x32_bf16(af, Bfr[sg * 2 + ci], acc[ci], 0, 0, 0);
        }
        #pragma unroll
        for (int rg = 0; rg < 4; ++rg) {
            int r = rowBase + hi * 4 + rg;
            float o0 = 0.f, o1 = 0.f;
            #pragma unroll
            for (int ci = 0; ci < 2; ++ci) {
                float v = lrelu(acc[ci][rg] + bv1[ci]);
                em[(size_t)r * 96 + (wv * 2 + ci) * 16 + lr] = v;
                o0 += v * w2v[0][ci];
                o1 += v * w2v[1][ci];
            }
            #pragma unroll
            for (int d = 1; d < 16; d <<= 1) {
                o0 += __shfl_xor(o0, d);
                o1 += __shfl_xor(o1, d);
            }
            if (lr == 0) {
                scrF[wv][hi * 4 + rg][0] = o0;
                scrF[wv][hi * 4 + rg][1] = o1;
            }
        }
    }
    __syncthreads();

    int tid = wv * 64 + lane;
    if (tid < 16) {
        int r = rowBase + tid;
        float o0 = scrF[0][tid][0] + scrF[1][tid][0] + scrF[2][tid][0] + b2[0];
        float o1 = scrF[0][tid][1] + scrF[1][tid][1] + scrF[2][tid][1] + b2[1];
        outp[r * 2 + 0] = o0;
        outp[r * 2 + 1] = o1;
    }
}

extern "C" void kernel_launch(void* const* d_in, const int* in_sizes, int n_in,
                              void* d_out, int out_size, void* d_ws, size_t ws_size,
                              hipStream_t stream)
{
    const float* pre_x = (const float*)d_in[0];
    const float* x     = (const float*)d_in[1];
    const int*   ei    = (const int*)d_in[2];
    const float* nprop = (const float*)d_in[4];
    const float* ncat  = (const float*)d_in[5];
    const float* des   = (const float*)d_in[6];
    const float* twt   = (const float*)d_in[7];
    const float* W_des  = (const float*)d_in[8],  *b_des  = (const float*)d_in[9];
    const float* W_tw   = (const float*)d_in[10], *b_tw   = (const float*)d_in[11];
    const float* W_tr   = (const float*)d_in[12], *b_tr   = (const float*)d_in[13];
    const float* W_prop = (const float*)d_in[14], *b_prop = (const float*)d_in[15];
    const float* W_cat  = (const float*)d_in[16], *b_cat  = (const float*)d_in[17];
    const float* W_text = (const float*)d_in[18], *b_text = (const float*)d_in[19];
    const float* W_in   = (const float*)d_in[20], *b_in   = (const float*)d_in[21];
    const float* W_c1   = (const float*)d_in[22], *b_c1   = (const float*)d_in[23];
    const float* W_c2   = (const float*)d_in[24], *b_c2   = (const float*)d_in[25];
    const float* W_o1   = (const float*)d_in[26], *b_o1   = (const float*)d_in[27];
    const float* W_o2   = (const float*)d_in[28], *b_o2   = (const float*)d_in[29];

    char* base = (char*)d_ws;
    size_t off = 0;
    auto alloc = [&](size_t bytes) -> char* {
        char* p = base + off;
        off = (off + bytes + 255) & ~(size_t)255;
        return p;
    };
    u16*   hA     = (u16*)alloc((size_t)NN * HD * 2);
    u16*   hB     = (u16*)alloc((size_t)NN * HD * 2);
    u16*   hC     = (u16*)alloc((size_t)NN * HD * 2);
    u16*   Wprep  = (u16*)alloc((size_t)227328 * 2);
    float* dinv   = (float*)alloc((size_t)NN * 4);
    float* invdeg = (float*)alloc((size_t)NN * 4);
    int*   deg    = (int*)alloc((size_t)NN * 4);
    int*   rp     = (int*)alloc((size_t)(NN + 1) * 4);
    int*   cursor = (int*)alloc((size_t)NN * 4);
    int*   part   = (int*)alloc(256 * 4);
    int*   cs     = (int*)alloc((size_t)EE * 4);
    float* nrm    = (float*)alloc((size_t)EE * 4);
    (void)ws_size; (void)in_sizes; (void)n_in; (void)out_size;

    float* outp = (float*)d_out;            // [N,2]
    float* em   = outp + (size_t)NN * 2;    // [N,96] fp32

    // ---- L0: prep ----
    hipMemsetAsync(deg, 0, (size_t)NN * 4, stream);
    hipLaunchKernelGGL(k_prep, dim3(144, 8), dim3(256), 0, stream,
        W_des, W_text, W_tw, W_tr, W_in, W_c1, W_c2, W_o1, Wprep);

    // ---- L1: branches (strided) + count riders ----
    hipLaunchKernelGGL(k_branch, dim3(256, 4), dim3(256), 0, stream,
        des, twt, pre_x, x, Wprep, b_des, b_text, b_tw, b_tr, hA, ei, deg);

    // ---- L2: small branches + scan1 ----
    hipLaunchKernelGGL(k_small_scan, dim3(1759), dim3(256), 0, stream,
        nprop, ncat, W_prop, b_prop, W_cat, b_cat, hA,
        deg, rp, part, dinv, invdeg);

    // ---- L3: h1 = lrelu(hA@W_in^T+b_in) -> hB   (+ scan3) ----
    hipLaunchKernelGGL((k_hgemm<true, true, 1>), dim3(587), dim3(512), 0, stream,
        hA, Wprep + 98304, b_in, hB,
        deg, rp, part, cursor, ei, cs, nrm, dinv);

    // ---- L4: hW1 = hB@W_c1^T -> hC   (+ fill) ----
    hipLaunchKernelGGL((k_hgemm<false, false, 2>), dim3(591), dim3(512), 0, stream,
        hB, Wprep + 98304 + 36864, nullptr, hC,
        deg, rp, part, cursor, ei, cs, nrm, dinv);

    // ---- L5': conv1(+b_c1) fused @W_c2 -> hA (= hW2) ----
    hipLaunchKernelGGL(k_aggemm, dim3(NN / 16), dim3(64, 4), 0, stream,
        hC, rp, cs, nrm, invdeg, b_c1, Wprep + 98304 + 2 * 36864, hA);

    // ---- L7': conv2(+b_c2) fused @Wo1/em/o2 -> d_out ----
    hipLaunchKernelGGL(k_aggfinal, dim3(NN / 16), dim3(64, 4), 0, stream,
        hA, rp, cs, nrm, invdeg, b_c2, Wprep + 208896, b_o1, W_o2, b_o2, em, outp);
}

// Round 15
// 369.586 us; speedup vs baseline: 1.1585x; 1.1585x over previous
//
#include <hip/hip_runtime.h>

#define NN 50000
#define EE 800000
#define LMD 768
#define HD 192
#define SLOPE 0.01f

typedef short bf16x8 __attribute__((ext_vector_type(8)));
typedef float f32x4 __attribute__((ext_vector_type(4)));
typedef unsigned short u16;

__device__ __forceinline__ float lrelu(float v){ return v > 0.f ? v : SLOPE * v; }

__device__ __forceinline__ u16 f2bf(float f){
    unsigned u = __float_as_uint(f);
    u += 0x7FFF + ((u >> 16) & 1u);
    return (u16)(u >> 16);
}
__device__ __forceinline__ float bf2f(u16 v){
    return __uint_as_float(((unsigned)v) << 16);
}
__device__ __forceinline__ bf16x8 as_bf8(float4 v){
    union { float4 f; bf16x8 b; } u; u.f = v; return u.b;
}

// ================= L0: weight prep (pure) =================
__global__ __launch_bounds__(256) void k_prep(
    const float* __restrict__ W0, const float* __restrict__ W1,
    const float* __restrict__ W2, const float* __restrict__ W3,
    const float* __restrict__ Win, const float* __restrict__ Wc1,
    const float* __restrict__ Wc2, const float* __restrict__ Wo1,
    u16* __restrict__ out)
{
    int m = blockIdx.y;
    int idx = blockIdx.x * 256 + threadIdx.x;
    const float* src; int nelem; int K;
    switch (m) {
      case 0: src = W0;  nelem = 32*768;  K = 768; break;
      case 1: src = W1;  nelem = 32*768;  K = 768; break;
      case 2: src = W2;  nelem = 32*768;  K = 768; break;
      case 3: src = W3;  nelem = 32*768;  K = 768; break;
      case 4: src = Win; nelem = 192*192; K = 192; break;
      case 5: src = Wc1; nelem = 192*192; K = 192; break;
      case 6: src = Wc2; nelem = 192*192; K = 192; break;
      default: src = Wo1; nelem = 96*192; K = 192; break;
    }
    if (idx >= nelem) return;
    u16 v = f2bf(src[idx]);
    int c = idx / K, k = idx - c * K;
    int cb = c >> 4, lr = c & 15;
    int sg = k >> 5, kk = k & 31, hi = kk >> 3, j = kk & 7;
    int lane = hi * 16 + lr;
    size_t dst;
    if (m < 4)      dst = (size_t)m * 24576 + (sg * 2 + cb) * 512 + lane * 8 + j;
    else if (m < 7) dst = 98304 + (size_t)(m - 4) * 36864 + (sg * 12 + cb) * 512 + lane * 8 + j;
    else            dst = 208896 + (size_t)(sg * 6 + cb) * 512 + lane * 8 + j;
    out[dst] = v;
}

// ================= L1: big branches STRIDED (x<192) + degree count riders (x>=192) =================
__global__ __launch_bounds__(256, 3) void k_branch(
    const float* __restrict__ des, const float* __restrict__ twt,
    const float* __restrict__ prex, const float* __restrict__ xx,
    const u16* __restrict__ Wf,
    const float* __restrict__ bd, const float* __restrict__ btx,
    const float* __restrict__ btw, const float* __restrict__ btr,
    u16* __restrict__ h,
    const int* __restrict__ ei, int* __restrict__ deg)
{
    __shared__ u16 Abuf[16][776];
    __shared__ float scr[4][16][32];

    if (blockIdx.x >= 192) {
        int rid = blockIdx.y * 64 + (blockIdx.x - 192);
        for (int e = rid * 256 + threadIdx.x; e < EE; e += 65536)
            atomicAdd(&deg[ei[EE + e]], 1);
        return;
    }

    const int br = blockIdx.y;
    const float* A; const float* bias; int colBase;
    switch (br) {
      case 0:  A = des;  bias = bd;  colBase = 64;  break;
      case 1:  A = twt;  bias = btx; colBase = 96;  break;
      case 2:  A = prex; bias = btw; colBase = 128; break;
      default: A = xx;   bias = btr; colBase = 160; break;
    }

    const int t0 = threadIdx.x, w = t0 >> 6, l = t0 & 63;
    const int hi = l >> 4, lr = l & 15;

    bf16x8 Bfr[12];
    {
        const u16* wp = Wf + br * 24576;
        #pragma unroll
        for (int cc = 0; cc < 6; ++cc)
            #pragma unroll
            for (int cb = 0; cb < 2; ++cb)
                Bfr[cc * 2 + cb] = *(const bf16x8*)(wp + ((w * 6 + cc) * 2 + cb) * 512 + l * 8);
    }

    const int rrow = t0 >> 4;
    const int col0 = (t0 & 15) * 2;
    const float bias0 = bias[col0], bias1 = bias[col0 + 1];

    float4 f4[12];
    int tile = blockIdx.x;
    {
        const float* ab = A + (size_t)tile * 12288 + w * 3072 + l * 4;
        #pragma unroll
        for (int i = 0; i < 12; ++i) f4[i] = *(const float4*)(ab + i * 256);
    }

    for (; tile < 3125; tile += 192) {
        asm volatile("s_waitcnt vmcnt(0)" ::: "memory");
        #pragma unroll
        for (int i = 0; i < 12; ++i) {
            const int rr = i / 3, third = i % 3;
            uint2 pk;
            pk.x = (unsigned)f2bf(f4[i].x) | ((unsigned)f2bf(f4[i].y) << 16);
            pk.y = (unsigned)f2bf(f4[i].z) | ((unsigned)f2bf(f4[i].w) << 16);
            *(uint2*)&Abuf[w * 4 + rr][third * 256 + l * 4] = pk;
        }
        const int tnext = tile + 192;
        if (tnext < 3125) {
            const float* ab = A + (size_t)tnext * 12288 + w * 3072 + l * 4;
            #pragma unroll
            for (int i = 0; i < 12; ++i) f4[i] = *(const float4*)(ab + i * 256);
        }
        __syncthreads();

        f32x4 acc[2] = {};
        #pragma unroll
        for (int cc = 0; cc < 6; ++cc) {
            const int cg = w * 6 + cc;
            bf16x8 af = *(const bf16x8*)&Abuf[lr][cg * 32 + hi * 8];
            acc[0] = __builtin_amdgcn_mfma_f32_16x16x32_bf16(af, Bfr[cc * 2 + 0], acc[0], 0, 0, 0);
            acc[1] = __builtin_amdgcn_mfma_f32_16x16x32_bf16(af, Bfr[cc * 2 + 1], acc[1], 0, 0, 0);
        }
        #pragma unroll
        for (int cb = 0; cb < 2; ++cb)
            #pragma unroll
            for (int rg = 0; rg < 4; ++rg)
                scr[w][hi * 4 + rg][cb * 16 + lr] = acc[cb][rg];
        __syncthreads();

        float2 s; s.x = 0.f; s.y = 0.f;
        #pragma unroll
        for (int ww = 0; ww < 4; ++ww) {
            float2 p = *(const float2*)&scr[ww][rrow][col0];
            s.x += p.x; s.y += p.y;
        }
        unsigned pk = (unsigned)f2bf(lrelu(s.x + bias0)) | ((unsigned)f2bf(lrelu(s.y + bias1)) << 16);
        *(unsigned*)&h[((size_t)tile * 16 + rrow) * HD + colBase + col0] = pk;
    }
}

// ================= L2: small branches (x<1563) + scan1 riders (x>=1563) =================
__global__ __launch_bounds__(256) void k_small_scan(
    const float* __restrict__ nprop, const float* __restrict__ ncat,
    const float* __restrict__ Wp, const float* __restrict__ bp,
    const float* __restrict__ Wc, const float* __restrict__ bc,
    u16* __restrict__ h,
    const int* __restrict__ deg, int* __restrict__ rp, int* __restrict__ part,
    float* __restrict__ dinv, float* __restrict__ invdeg)
{
    if (blockIdx.x >= 1563) {
        __shared__ int sh[256];
        int sb = blockIdx.x - 1563;
        int tid = threadIdx.x;
        int i = sb * 256 + tid;
        int x = (i < NN) ? deg[i] : 0;
        if (i < NN) {
            float d = (float)(x + 1);
            dinv[i] = rsqrtf(d);
            invdeg[i] = 1.0f / d;
        }
        sh[tid] = x;
        __syncthreads();
        for (int off = 1; off < 256; off <<= 1) {
            int y = (tid >= off) ? sh[tid - off] : 0;
            __syncthreads();
            sh[tid] += y;
            __syncthreads();
        }
        if (i < NN) rp[i] = sh[tid] - x;
        if (tid == 255) part[sb] = sh[255];
        return;
    }

    __shared__ float sWp[160], sbp[32], sWc[32], sbc[32];
    int t = threadIdx.x;
    if (t < 160) sWp[t] = Wp[t];
    else if (t < 192) sbp[t - 160] = bp[t - 160];
    else if (t < 224) sWc[t - 192] = Wc[t - 192];
    else              sbc[t - 224] = bc[t - 224];
    __syncthreads();

    int idx = blockIdx.x * 256 + t;
    if (idx >= NN * 8) return;
    int row = idx >> 3, g = idx & 7;
    float o[8];
    if (g < 4) {
        float np[5];
        #pragma unroll
        for (int k = 0; k < 5; ++k) np[k] = nprop[row * 5 + k];
        #pragma unroll
        for (int j = 0; j < 8; ++j) {
            int c = g * 8 + j;
            float a = sbp[c];
            #pragma unroll
            for (int k = 0; k < 5; ++k) a += np[k] * sWp[c * 5 + k];
            o[j] = lrelu(a);
        }
    } else {
        float nc = ncat[row];
        #pragma unroll
        for (int j = 0; j < 8; ++j) {
            int cc = (g - 4) * 8 + j;
            o[j] = lrelu(sbc[cc] + nc * sWc[cc]);
        }
    }
    uint4 pk;
    pk.x = (unsigned)f2bf(o[0]) | ((unsigned)f2bf(o[1]) << 16);
    pk.y = (unsigned)f2bf(o[2]) | ((unsigned)f2bf(o[3]) << 16);
    pk.z = (unsigned)f2bf(o[4]) | ((unsigned)f2bf(o[5]) << 16);
    pk.w = (unsigned)f2bf(o[6]) | ((unsigned)f2bf(o[7]) << 16);
    *(uint4*)&h[(size_t)row * HD + g * 8] = pk;
}

// ================= hidden GEMM + optional graph-build rider role =================
// ROLE: 0 = none, 1 = scan3 (x>=391), 2 = fill (x>=391)
template<bool BIAS, bool LRELU, int ROLE>
__global__ __launch_bounds__(512) void k_hgemm(
    const u16* __restrict__ A, const u16* __restrict__ Wf,
    const float* __restrict__ bias, u16* __restrict__ out,
    const int* __restrict__ deg, int* __restrict__ rp, const int* __restrict__ part,
    int* __restrict__ cursor, const int* __restrict__ ei,
    int* __restrict__ cs, float* __restrict__ nrm, const float* __restrict__ dinv)
{
    __shared__ u16 Bs[36864];
    if (ROLE == 1 && blockIdx.x >= 391) {
        int sb = blockIdx.x - 391;
        int tid = threadIdx.x;
        if (tid < 256) {
            int pre = 0;
            for (int j = 0; j < sb; ++j) pre += part[j];
            int i = sb * 256 + tid;
            if (i < NN) {
                int v = rp[i] + pre;
                rp[i] = v;
                cursor[i] = v;
                if (i == NN - 1) rp[NN] = v + deg[i];
            }
        }
        return;
    }
    if (ROLE == 2 && blockIdx.x >= 391) {
        int rid = blockIdx.x - 391;
        for (int e = rid * 512 + threadIdx.x; e < EE; e += 102400) {
            int s = ei[e], d = ei[EE + e];
            int pos = atomicAdd(&cursor[d], 1);
            cs[pos] = s;
            nrm[pos] = dinv[s] * dinv[d];
        }
        return;
    }

    const int t = threadIdx.x, w = t >> 6, l = t & 63;
    const int hi = l >> 4, lr = l & 15;
    const int rowBase = blockIdx.x * 128;
    {
        const uint4* s_ = (const uint4*)Wf; uint4* d_ = (uint4*)Bs;
        #pragma unroll
        for (int i = 0; i < 9; ++i) d_[i * 512 + t] = s_[i * 512 + t];
    }
    int r0 = rowBase + w * 16 + lr;
    int rowc = r0 < NN ? r0 : NN - 1;
    const u16* ap = A + (size_t)rowc * HD;
    float4 araw[6];
    #pragma unroll
    for (int sg = 0; sg < 6; ++sg) {
        araw[sg] = *(const float4*)(ap + sg * 32 + hi * 8);
        asm volatile("" :: "v"(araw[sg].x), "v"(araw[sg].y), "v"(araw[sg].z), "v"(araw[sg].w));
    }
    __syncthreads();

    f32x4 acc[12] = {};
    #pragma unroll
    for (int sg = 0; sg < 6; ++sg) {
        bf16x8 af = as_bf8(araw[sg]);
        #pragma unroll
        for (int cb = 0; cb < 12; ++cb) {
            bf16x8 bf = *(const bf16x8*)(Bs + (sg * 12 + cb) * 512 + l * 8);
            acc[cb] = __builtin_amdgcn_mfma_f32_16x16x32_bf16(af, bf, acc[cb], 0, 0, 0);
        }
    }

    #pragma unroll
    for (int cb = 0; cb < 12; ++cb) {
        int cl = cb * 16 + lr;
        float bv = BIAS ? bias[cl] : 0.f;
        #pragma unroll
        for (int rg = 0; rg < 4; ++rg) {
            int r = rowBase + w * 16 + hi * 4 + rg;
            if (r < NN) {
                float v = acc[cb][rg] + bv;
                if (LRELU) v = lrelu(v);
                out[(size_t)r * HD + cl] = f2bf(v);
            }
        }
    }
}

// ================= final: em = lrelu(hC @ Wo1^T + b1) fp32 + out = em @ Wo2^T + b2 =================
__global__ __launch_bounds__(512) void k_final(
    const u16* __restrict__ A, const u16* __restrict__ Wf,
    const float* __restrict__ b1, const float* __restrict__ W2,
    const float* __restrict__ b2, float* __restrict__ em, float* __restrict__ out)
{
    __shared__ u16 Bs[18432];
    const int t = threadIdx.x, w = t >> 6, l = t & 63;
    const int hi = l >> 4, lr = l & 15;
    const int rowBase = blockIdx.x * 128;
    {
        const uint4* s_ = (const uint4*)Wf; uint4* d_ = (uint4*)Bs;
        #pragma unroll
        for (int i = 0; i < 5; ++i) { int idx = i * 512 + t; if (idx < 2304) d_[idx] = s_[idx]; }
    }
    int r0 = rowBase + w * 16 + lr;
    int rowc = r0 < NN ? r0 : NN - 1;
    const u16* ap = A + (size_t)rowc * HD;
    float4 araw[6];
    #pragma unroll
    for (int sg = 0; sg < 6; ++sg) {
        araw[sg] = *(const float4*)(ap + sg * 32 + hi * 8);
        asm volatile("" :: "v"(araw[sg].x), "v"(araw[sg].y), "v"(araw[sg].z), "v"(araw[sg].w));
    }
    __syncthreads();

    f32x4 acc[6] = {};
    #pragma unroll
    for (int sg = 0; sg < 6; ++sg) {
        bf16x8 af = as_bf8(araw[sg]);
        #pragma unroll
        for (int cb = 0; cb < 6; ++cb) {
            bf16x8 bf = *(const bf16x8*)(Bs + (sg * 6 + cb) * 512 + l * 8);
            acc[cb] = __builtin_amdgcn_mfma_f32_16x16x32_bf16(af, bf, acc[cb], 0, 0, 0);
        }
    }

    float w2v[2][6], bv[6];
    #pragma unroll
    for (int cb = 0; cb < 6; ++cb) {
        bv[cb] = b1[cb * 16 + lr];
        w2v[0][cb] = W2[cb * 16 + lr];
        w2v[1][cb] = W2[96 + cb * 16 + lr];
    }

    #pragma unroll
    for (int rg = 0; rg < 4; ++rg) {
        int r = rowBase + w * 16 + hi * 4 + rg;
        float o0 = 0.f, o1 = 0.f;
        #pragma unroll
        for (int cb = 0; cb < 6; ++cb) {
            float v = lrelu(acc[cb][rg] + bv[cb]);
            if (r < NN) em[(size_t)r * 96 + cb * 16 + lr] = v;
            o0 += v * w2v[0][cb];
            o1 += v * w2v[1][cb];
        }
        #pragma unroll
        for (int d = 1; d < 16; d <<= 1) {
            o0 += __shfl_xor(o0, d);
            o1 += __shfl_xor(o1, d);
        }
        if (lr == 0 && r < NN) {
            out[r * 2 + 0] = o0 + b2[0];
            out[r * 2 + 1] = o1 + b2[1];
        }
    }
}

// ================= GCN aggregation: 1 wave/node (48 active lanes), 8-deep unroll =================
__global__ __launch_bounds__(256) void k_agg(const u16* __restrict__ hW,
    const int* __restrict__ rp, const int* __restrict__ cs, const float* __restrict__ nrm,
    const float* __restrict__ invdeg, const float* __restrict__ bias, u16* __restrict__ out)
{
    int lane = threadIdx.x;
    if (lane >= 48) return;
    int v = blockIdx.x * 4 + threadIdx.y;
    int f0 = lane * 4;
    int s0 = rp[v], s1 = rp[v + 1];
    float4 bv = *reinterpret_cast<const float4*>(bias + f0);
    ushort4 hv = *reinterpret_cast<const ushort4*>(hW + (size_t)v * HD + f0);
    float idg = invdeg[v];
    float a0 = bf2f(hv.x) * idg + bv.x;
    float a1 = bf2f(hv.y) * idg + bv.y;
    float a2 = bf2f(hv.z) * idg + bv.z;
    float a3 = bf2f(hv.w) * idg + bv.w;
    int i = s0;
    for (; i + 8 <= s1; i += 8) {
        int c[8]; float n[8]; ushort4 g[8];
        #pragma unroll
        for (int j = 0; j < 8; ++j) { c[j] = cs[i + j]; n[j] = nrm[i + j]; }
        #pragma unroll
        for (int j = 0; j < 8; ++j)
            g[j] = *reinterpret_cast<const ushort4*>(hW + (size_t)c[j] * HD + f0);
        #pragma unroll
        for (int j = 0; j < 8; ++j) {
            a0 += bf2f(g[j].x) * n[j]; a1 += bf2f(g[j].y) * n[j];
            a2 += bf2f(g[j].z) * n[j]; a3 += bf2f(g[j].w) * n[j];
        }
    }
    for (; i < s1; ++i) {
        int c = cs[i]; float n = nrm[i];
        ushort4 g = *reinterpret_cast<const ushort4*>(hW + (size_t)c * HD + f0);
        a0 += bf2f(g.x) * n; a1 += bf2f(g.y) * n; a2 += bf2f(g.z) * n; a3 += bf2f(g.w) * n;
    }
    ushort4 o;
    o.x = f2bf(a0); o.y = f2bf(a1); o.z = f2bf(a2); o.w = f2bf(a3);
    *reinterpret_cast<ushort4*>(out + (size_t)v * HD + f0) = o;
}

extern "C" void kernel_launch(void* const* d_in, const int* in_sizes, int n_in,
                              void* d_out, int out_size, void* d_ws, size_t ws_size,
                              hipStream_t stream)
{
    const float* pre_x = (const float*)d_in[0];
    const float* x     = (const float*)d_in[1];
    const int*   ei    = (const int*)d_in[2];
    const float* nprop = (const float*)d_in[4];
    const float* ncat  = (const float*)d_in[5];
    const float* des   = (const float*)d_in[6];
    const float* twt   = (const float*)d_in[7];
    const float* W_des  = (const float*)d_in[8],  *b_des  = (const float*)d_in[9];
    const float* W_tw   = (const float*)d_in[10], *b_tw   = (const float*)d_in[11];
    const float* W_tr   = (const float*)d_in[12], *b_tr   = (const float*)d_in[13];
    const float* W_prop = (const float*)d_in[14], *b_prop = (const float*)d_in[15];
    const float* W_cat  = (const float*)d_in[16], *b_cat  = (const float*)d_in[17];
    const float* W_text = (const float*)d_in[18], *b_text = (const float*)d_in[19];
    const float* W_in   = (const float*)d_in[20], *b_in   = (const float*)d_in[21];
    const float* W_c1   = (const float*)d_in[22], *b_c1   = (const float*)d_in[23];
    const float* W_c2   = (const float*)d_in[24], *b_c2   = (const float*)d_in[25];
    const float* W_o1   = (const float*)d_in[26], *b_o1   = (const float*)d_in[27];
    const float* W_o2   = (const float*)d_in[28], *b_o2   = (const float*)d_in[29];

    char* base = (char*)d_ws;
    size_t off = 0;
    auto alloc = [&](size_t bytes) -> char* {
        char* p = base + off;
        off = (off + bytes + 255) & ~(size_t)255;
        return p;
    };
    u16*   hA     = (u16*)alloc((size_t)NN * HD * 2);
    u16*   hB     = (u16*)alloc((size_t)NN * HD * 2);
    u16*   hC     = (u16*)alloc((size_t)NN * HD * 2);
    u16*   Wprep  = (u16*)alloc((size_t)227328 * 2);
    float* dinv   = (float*)alloc((size_t)NN * 4);
    float* invdeg = (float*)alloc((size_t)NN * 4);
    int*   deg    = (int*)alloc((size_t)NN * 4);
    int*   rp     = (int*)alloc((size_t)(NN + 1) * 4);
    int*   cursor = (int*)alloc((size_t)NN * 4);
    int*   part   = (int*)alloc(256 * 4);
    int*   cs     = (int*)alloc((size_t)EE * 4);
    float* nrm    = (float*)alloc((size_t)EE * 4);
    (void)ws_size; (void)in_sizes; (void)n_in; (void)out_size;

    float* outp = (float*)d_out;            // [N,2]
    float* em   = outp + (size_t)NN * 2;    // [N,96] fp32

    // ---- L0: prep (pure) ----
    hipMemsetAsync(deg, 0, (size_t)NN * 4, stream);
    hipLaunchKernelGGL(k_prep, dim3(144, 8), dim3(256), 0, stream,
        W_des, W_text, W_tw, W_tr, W_in, W_c1, W_c2, W_o1, Wprep);

    // ---- L1: branches (strided) + count riders ----
    hipLaunchKernelGGL(k_branch, dim3(256, 4), dim3(256), 0, stream,
        des, twt, pre_x, x, Wprep, b_des, b_text, b_tw, b_tr, hA, ei, deg);

    // ---- L2: small branches + scan1 ----
    hipLaunchKernelGGL(k_small_scan, dim3(1759), dim3(256), 0, stream,
        nprop, ncat, W_prop, b_prop, W_cat, b_cat, hA,
        deg, rp, part, dinv, invdeg);

    // ---- L3: h1 = lrelu(hA@W_in^T+b_in) -> hB   (+ scan3) ----
    hipLaunchKernelGGL((k_hgemm<true, true, 1>), dim3(587), dim3(512), 0, stream,
        hA, Wprep + 98304, b_in, hB,
        deg, rp, part, cursor, ei, cs, nrm, dinv);

    // ---- L4: hW1 = hB@W_c1^T -> hC   (+ fill) ----
    hipLaunchKernelGGL((k_hgemm<false, false, 2>), dim3(591), dim3(512), 0, stream,
        hB, Wprep + 98304 + 36864, nullptr, hC,
        deg, rp, part, cursor, ei, cs, nrm, dinv);

    // ---- L5: conv1 -> hB ----
    hipLaunchKernelGGL(k_agg, dim3(NN / 4), dim3(64, 4), 0, stream,
        hC, rp, cs, nrm, invdeg, b_c1, hB);

    // ---- L6: hW2 = hB@W_c2^T -> hC ----
    hipLaunchKernelGGL((k_hgemm<false, false, 0>), dim3(391), dim3(512), 0, stream,
        hB, Wprep + 98304 + 2 * 36864, nullptr, hC,
        deg, rp, part, cursor, ei, cs, nrm, dinv);

    // ---- L7: conv2 -> hB ----
    hipLaunchKernelGGL(k_agg, dim3(NN / 4), dim3(64, 4), 0, stream,
        hC, rp, cs, nrm, invdeg, b_c2, hB);

    // ---- L8: em + out ----
    hipLaunchKernelGGL(k_final, dim3(391), dim3(512), 0, stream,
        hB, Wprep + 208896, b_o1, W_o2, b_o2, em, outp);
}